// Round 5
// baseline (182.326 us; speedup 1.0000x reference)
//
#include <hip/hip_runtime.h>
#include <hip/hip_bf16.h>
#include <math.h>

// InteractionBlock R5: 2 dispatches.
//  prep:  head[]=-1, ctrs=0, pack W2 -> pre-swizzled bf16 MFMA B-fragments.
//  fused: blocks [0,niB): interact (geometry -> compaction -> MFMA GEMM -> factored
//         bf16 message rows + per-dst linked list), then release edges_done.
//         blocks [niB, niB+NGB): spin on edges_done (relaxed + s_sleep, acquire on
//         exit), then grid-stride the per-node list gather, writing out exactly once.
//  Deadlock-proof: spinners <= 256 blocks; __launch_bounds__(256,4) + 34KB LDS
//  guarantee >=2 blocks/CU (512 slots), so producers always make progress.

typedef __attribute__((ext_vector_type(8))) short short8;
typedef __attribute__((ext_vector_type(4))) float f32x4;
typedef __attribute__((ext_vector_type(4))) unsigned short u16x4;

#define DSTRIDE 72   // ushorts per data row (144 B, 16B-aligned)
#define NGB 256      // gather blocks

static __device__ __forceinline__ unsigned short f2bf(float f) {
  __hip_bfloat16 h = __float2bfloat16(f);   // RNE; pairs fuse to v_cvt_pk_bf16_f32
  return __builtin_bit_cast(unsigned short, h);
}
static __device__ __forceinline__ float bf2f(unsigned short s) {
  unsigned u = ((unsigned)s) << 16;
  return __builtin_bit_cast(float, u);
}

// ---- prep: head init + ctr zero + W2 -> bf16 B-fragments ----
// frag fi = s*3+t (s=k-step 0..7, t=n-tile 0..2); entry (fi,lane,j):
//   k_global = s*32 + (lane>>4)*8 + j, n = t*16 + (lane&15)
//   W2r[k][n] = W2[kk*768 + t*256 + c*16 + h], kk=k>>4, c=k&15, h=lane&15
__global__ __launch_bounds__(256)
void prep_kernel(const float* __restrict__ W2, unsigned short* __restrict__ w2f,
                 int* __restrict__ head, int* __restrict__ ctrs, int N) {
  int gid = blockIdx.x * 256 + threadIdx.x;
  if (gid < N) head[gid] = -1;
  if (gid < 16) ctrs[gid] = 0;
  if (gid < 24 * 64) {
    int fi = gid >> 6, lane = gid & 63;
    int s = fi / 3, t = fi - 3 * s;
    int h = lane & 15, kq = lane >> 4;
    short8 pack;
    #pragma unroll
    for (int j = 0; j < 8; ++j) {
      int kg = s * 32 + kq * 8 + j;
      int kk = kg >> 4, c = kg & 15;
      pack[j] = (short)f2bf(W2[kk * 768 + t * 256 + c * 16 + h]);
    }
    *(short8*)&w2f[(size_t)gid * 8] = pack;
  }
}

// ---- fused: interact (producer) + gather (consumer) ----
__global__ __launch_bounds__(256, 4)
void fused_kernel(const float* __restrict__ xfeat,
                  const float* __restrict__ coords,
                  const int* __restrict__ eidx,
                  const float* __restrict__ W1g,
                  const unsigned short* __restrict__ w2f,
                  unsigned short* __restrict__ data,  // [E][72] bf16
                  int* __restrict__ head,             // [N] == -1 from prep
                  int* __restrict__ next,             // [E]
                  int* __restrict__ ctrs,             // [16] zeroed by prep
                  float* __restrict__ out,
                  int E, int N, int niB)
{
  __shared__ __align__(16) float W1s[256];
  __shared__ float hsS[256 * 20];                        // stride 20 f32 (80B)
  __shared__ __align__(16) unsigned short xsS[256 * 24]; // stride 24 ush (48B)
  __shared__ int eS[256];
  __shared__ int wsum[4];

  const int bid = blockIdx.x;
  const int tid = threadIdx.x;

  if (bid < niB) {
    // ================= interact role =================
    const int lane = tid & 63, wid = tid >> 6;
    W1s[tid] = W1g[tid];

    const int e = bid * 256 + tid;
    bool act = false;
    int src = 0, dst = 0;
    float rx = 0.f, ry = 0.f, rz = 0.f, d2 = 0.f;
    if (e < E) {
      src = eidx[e]; dst = eidx[E + e];
      rx = coords[3*src]   - coords[3*dst];
      ry = coords[3*src+1] - coords[3*dst+1];
      rz = coords[3*src+2] - coords[3*dst+2];
      d2 = rx*rx + ry*ry + rz*rz;
      act = (d2 > 0.0f) && (d2 < 36.0f);
    }
    unsigned long long bm = __ballot(act);
    int pfx = __popcll(bm & ((1ull << lane) - 1ull));
    if (lane == 0) wsum[wid] = __popcll(bm);
    __syncthreads();                                   // covers W1s + wsum
    int base = 0;
    #pragma unroll
    for (int w = 0; w < 4; ++w) base += (w < wid) ? wsum[w] : 0;
    const int total = wsum[0] + wsum[1] + wsum[2] + wsum[3];
    const int cpos = base + pfx;

    if (act) {
      float dd  = sqrtf(d2);
      float inv = 1.0f / dd;
      float x = rx*inv, y = ry*inv, z = rz*inv;
      const float A1 = 0.48860251190291992f;  // sqrt(3)/sqrt(4pi)
      const float A2 = 1.09254843059207907f;  // sqrt(15)/sqrt(4pi)
      const float A3 = 0.63078313050504001f;  // sqrt(5)/sqrt(4pi)
      unsigned short* dr = data + (size_t)e * DSTRIDE;
      short8 ys;
      ys[0] = (short)f2bf(A1*x);   ys[1] = (short)f2bf(A1*y);  ys[2] = (short)f2bf(A1*z);
      ys[3] = (short)f2bf(A2*x*z); ys[4] = (short)f2bf(A2*x*y);
      ys[5] = (short)f2bf(A3*(y*y - 0.5f*(x*x + z*z)));
      ys[6] = (short)f2bf(A2*y*z); ys[7] = (short)f2bf(0.5f*A2*(z*z - x*x));
      *(short8*)&dr[64] = ys;
      next[e] = atomicExch(&head[dst], e);   // device-scope

      // bessel -> hidden: h[j] = gain*silu( (eb@W1)[j]/4 ), float4 LDS reads
      float theta = 0.52359877559829887f * dd;   // pi/6 * d
      float s1 = __sinf(theta), c1 = __cosf(theta);
      float snm = 0.0f, sn = s1;
      float4 hbv[4];
      #pragma unroll
      for (int q = 0; q < 4; ++q) hbv[q] = make_float4(0.f, 0.f, 0.f, 0.f);
      #pragma unroll
      for (int k = 0; k < 16; ++k) {
        #pragma unroll
        for (int q = 0; q < 4; ++q) {
          const float4 w = *((const float4*)&W1s[k*16 + q*4]);
          hbv[q].x = fmaf(sn, w.x, hbv[q].x);
          hbv[q].y = fmaf(sn, w.y, hbv[q].y);
          hbv[q].z = fmaf(sn, w.z, hbv[q].z);
          hbv[q].w = fmaf(sn, w.w, hbv[q].w);
        }
        float sp = 2.0f*c1*sn - snm;
        snm = sn; sn = sp;
      }
      const float scale1 = 2.30940107675850305f * inv * 0.25f;
      float* hrow = &hsS[cpos * 20];
      #pragma unroll
      for (int q = 0; q < 4; ++q) {
        float b[4] = {hbv[q].x, hbv[q].y, hbv[q].z, hbv[q].w};
        #pragma unroll
        for (int r = 0; r < 4; ++r) {
          float p = b[r] * scale1;
          hrow[q*4 + r] = 1.679177f * p / (1.0f + __expf(-p));
        }
      }
      unsigned short* xrow = &xsS[cpos * 24];
      #pragma unroll
      for (int cc = 0; cc < 4; ++cc) {
        float4 xv = *(const float4*)&xfeat[src*16 + cc*4];
        xrow[cc*4+0] = f2bf(xv.x); xrow[cc*4+1] = f2bf(xv.y);
        xrow[cc*4+2] = f2bf(xv.z); xrow[cc*4+3] = f2bf(xv.w);
      }
      eS[cpos] = e;
    }
    const int padded = (total + 15) & ~15;
    if (tid >= total && tid < padded) {       // zero pad rows
      #pragma unroll
      for (int j = 0; j < 16; ++j) hsS[tid*20 + j] = 0.0f;
      #pragma unroll
      for (int j = 0; j < 16; ++j) xsS[tid*24 + j] = 0;
    }
    __syncthreads();

    // ---- MFMA GEMM [padded,256] x [256,48] ----
    short8 bfr[8][3];
    #pragma unroll
    for (int s = 0; s < 8; ++s)
      #pragma unroll
      for (int t = 0; t < 3; ++t)
        bfr[s][t] = *(const short8*)&w2f[(size_t)((s*3 + t)*64 + lane) * 8];

    const int ngroups = padded >> 4;
    const int ma = lane & 15, kq = lane >> 4;
    const int c0 = (kq & 1) * 8;
    for (int g = wid; g < ngroups; g += 4) {
      const int cidx = g*16 + ma;
      const float* hrow = &hsS[cidx * 20];
      const unsigned short* xrow = &xsS[cidx * 24];
      float xsf[8];
      #pragma unroll
      for (int j = 0; j < 8; ++j) xsf[j] = bf2f(xrow[c0 + j]);

      f32x4 acc0 = {0,0,0,0}, acc1 = {0,0,0,0}, acc2 = {0,0,0,0};
      #pragma unroll
      for (int s = 0; s < 8; ++s) {
        const float hk = hrow[2*s + (kq >> 1)];
        short8 a;
        #pragma unroll
        for (int j = 0; j < 8; ++j) a[j] = (short)f2bf(hk * xsf[j]);
        acc0 = __builtin_amdgcn_mfma_f32_16x16x32_bf16(a, bfr[s][0], acc0, 0, 0, 0);
        acc1 = __builtin_amdgcn_mfma_f32_16x16x32_bf16(a, bfr[s][1], acc1, 0, 0, 0);
        acc2 = __builtin_amdgcn_mfma_f32_16x16x32_bf16(a, bfr[s][2], acc2, 0, 0, 0);
      }
      // D layout: row = kq*4 + r, col = lane&15  (m89-verified)
      const float sc = 0.00390625f;  // 1/256
      #pragma unroll
      for (int r = 0; r < 4; ++r) {
        const int cr = g*16 + kq*4 + r;
        if (cr < total) {
          unsigned short* dr = data + (size_t)eS[cr] * DSTRIDE;
          u16x4 vv;
          vv[0] = f2bf(acc0[r] * sc);
          vv[1] = f2bf(acc1[r] * sc);
          vv[2] = f2bf(acc2[r] * sc);
          vv[3] = 0;
          *(u16x4*)&dr[ma * 4] = vv;
        }
      }
    }

    // ---- publish ----
    __threadfence();     // per-thread: make data/next visible agent-wide
    __syncthreads();     // all threads of block have fenced
    if (tid == 0)
      __hip_atomic_fetch_add(&ctrs[1], 1, __ATOMIC_RELEASE, __HIP_MEMORY_SCOPE_AGENT);
  } else {
    // ================= gather role =================
    if (tid == 0) {
      while (__hip_atomic_load(&ctrs[1], __ATOMIC_RELAXED, __HIP_MEMORY_SCOPE_AGENT) < niB)
        __builtin_amdgcn_s_sleep(32);
      __hip_atomic_load(&ctrs[1], __ATOMIC_ACQUIRE, __HIP_MEMORY_SCOPE_AGENT);
    }
    __syncthreads();

    const int nchunks = (N + 15) >> 4;
    const int h = tid & 15, s16 = tid >> 4;
    for (int c = bid - niB; c < nchunks; c += NGB) {
      const int node = c * 16 + s16;
      if (node >= N) continue;
      float a0 = 0.f;
      float a10 = 0.f, a11 = 0.f, a12 = 0.f;
      float a20 = 0.f, a21 = 0.f, a22 = 0.f, a23 = 0.f, a24 = 0.f;

      int p = head[node];
      while (p >= 0) {
        const unsigned short* dr = data + (size_t)p * DSTRIDE;
        int pn = next[p];
        u16x4 vv = *(const u16x4*)&dr[h * 4];
        short8 yv = *(const short8*)&dr[64];
        float v0 = bf2f(vv[0]), v1 = bf2f(vv[1]), v2 = bf2f(vv[2]);
        a0  += v0;
        a10 = fmaf(v1, bf2f((unsigned short)yv[0]), a10);
        a11 = fmaf(v1, bf2f((unsigned short)yv[1]), a11);
        a12 = fmaf(v1, bf2f((unsigned short)yv[2]), a12);
        a20 = fmaf(v2, bf2f((unsigned short)yv[3]), a20);
        a21 = fmaf(v2, bf2f((unsigned short)yv[4]), a21);
        a22 = fmaf(v2, bf2f((unsigned short)yv[5]), a22);
        a23 = fmaf(v2, bf2f((unsigned short)yv[6]), a23);
        a24 = fmaf(v2, bf2f((unsigned short)yv[7]), a24);
        p = pn;
      }

      float* o = out + (size_t)node * 144;
      o[h] = a0 * 0.28209479177387814f;   // Y0 constant folded here
      o[16 + h*3 + 0] = a10;
      o[16 + h*3 + 1] = a11;
      o[16 + h*3 + 2] = a12;
      o[64 + h*5 + 0] = a20;
      o[64 + h*5 + 1] = a21;
      o[64 + h*5 + 2] = a22;
      o[64 + h*5 + 3] = a23;
      o[64 + h*5 + 4] = a24;
    }
  }
}

extern "C" void kernel_launch(void* const* d_in, const int* in_sizes, int n_in,
                              void* d_out, int out_size, void* d_ws, size_t ws_size,
                              hipStream_t stream) {
  const float* xfeat  = (const float*)d_in[0];
  const float* coords = (const float*)d_in[1];
  const int*   eidx   = (const int*)d_in[2];
  const float* W1     = (const float*)d_in[3];
  const float* W2     = (const float*)d_in[4];
  float* out = (float*)d_out;

  const int E = in_sizes[2] / 2;
  const int N = out_size / 144;
  const int niB = (E + 255) / 256;

  // ws layout (16B-aligned): data bf16[E][72] | head[N pad4] | next[E] | w2f | ctrs
  char* ws = (char*)d_ws;
  size_t off_head = (size_t)E * DSTRIDE * sizeof(unsigned short);
  size_t off_next = off_head + (size_t)((N + 3) & ~3) * sizeof(int);
  size_t off_w2f  = off_next + (size_t)E * sizeof(int);
  size_t off_ctr  = off_w2f + 24576;
  unsigned short* data = (unsigned short*)ws;
  int* head = (int*)(ws + off_head);
  int* next = (int*)(ws + off_next);
  unsigned short* w2f = (unsigned short*)(ws + off_w2f);
  int* ctrs = (int*)(ws + off_ctr);

  int pblk = (N + 255) / 256;
  if (pblk < 6) pblk = 6;
  prep_kernel<<<pblk, 256, 0, stream>>>(W2, w2f, head, ctrs, N);
  fused_kernel<<<niB + NGB, 256, 0, stream>>>(xfeat, coords, eidx, W1, w2f,
                                              data, head, next, ctrs, out, E, N, niB);
}

// Round 6
// 43.257 us; speedup vs baseline: 4.2149x; 4.2149x over previous
//
#include <hip/hip_runtime.h>
#include <hip/hip_bf16.h>
#include <math.h>

// InteractionBlock R6 (revert R5 fusion; bucket-CSR scatter).
//  prep:  cnt[]=0 + pack W2 into pre-swizzled bf16 MFMA B-fragments.
//  K1:    per-edge geometry/bessel-MLP -> ballot compaction -> MFMA GEMM
//         [E,256](q = h (x) xs) x [256,48](W2 frags in VGPRs) -> factored bf16
//         message rows data[e] = { v[16][4], Y1..Y8 }; slot = atomicAdd(cnt[dst]),
//         bucket[dst*64+slot] = e  (no dependent atomicExch chain).
//  K2:    per-node gather over bucket entries (independent loads, no pointer
//         chase), expand msg = v_l[h]*Y[m], write out exactly once.
// R5 lesson: cross-block fusion needs agent-scope fences -> L2 writeback storm
// on 8 non-coherent XCDs (177us). Kernel boundary IS the cheap flush.

typedef __attribute__((ext_vector_type(8))) short short8;
typedef __attribute__((ext_vector_type(4))) float f32x4;
typedef __attribute__((ext_vector_type(4))) unsigned short u16x4;

#define DSTRIDE 72   // ushorts per data row (144 B, 16B-aligned)
#define CAP 64       // bucket capacity per node (active degree ~Poisson(6.86))

static __device__ __forceinline__ unsigned short f2bf(float f) {
  __hip_bfloat16 h = __float2bfloat16(f);   // RNE; pairs fuse to v_cvt_pk_bf16_f32
  return __builtin_bit_cast(unsigned short, h);
}
static __device__ __forceinline__ float bf2f(unsigned short s) {
  unsigned u = ((unsigned)s) << 16;
  return __builtin_bit_cast(float, u);
}

// ---- prep: cnt=0 + W2 -> bf16 B-fragments ----
// frag fi = s*3+t (s=k-step 0..7, t=n-tile 0..2); entry (fi,lane,j):
//   k_global = s*32 + (lane>>4)*8 + j, n = t*16 + (lane&15)
//   W2r[k][n] = W2[kk*768 + t*256 + c*16 + h], kk=k>>4, c=k&15, h=lane&15
__global__ __launch_bounds__(256)
void prep_kernel(const float* __restrict__ W2, unsigned short* __restrict__ w2f,
                 int* __restrict__ cnt, int N) {
  int gid = blockIdx.x * 256 + threadIdx.x;
  if (gid < N) cnt[gid] = 0;
  if (gid < 24 * 64) {
    int fi = gid >> 6, lane = gid & 63;
    int s = fi / 3, t = fi - 3 * s;
    int h = lane & 15, kq = lane >> 4;
    short8 pack;
    #pragma unroll
    for (int j = 0; j < 8; ++j) {
      int kg = s * 32 + kq * 8 + j;
      int kk = kg >> 4, c = kg & 15;
      pack[j] = (short)f2bf(W2[kk * 768 + t * 256 + c * 16 + h]);
    }
    *(short8*)&w2f[(size_t)gid * 8] = pack;
  }
}

// ---- K1: per-edge features + compaction + MFMA GEMM + factored-message write ----
__global__ __launch_bounds__(256, 4)
void interact_kernel(const float* __restrict__ xfeat,
                     const float* __restrict__ coords,
                     const int* __restrict__ eidx,
                     const float* __restrict__ W1g,
                     const unsigned short* __restrict__ w2f,
                     unsigned short* __restrict__ data,  // [E][72] bf16
                     int* __restrict__ cnt,              // [N] zeroed
                     int* __restrict__ bucket,           // [N][CAP]
                     int E)
{
  __shared__ __align__(16) float W1s[256];
  __shared__ float hsS[256 * 20];                        // stride 20 f32 (80B)
  __shared__ __align__(16) unsigned short xsS[256 * 24]; // stride 24 ush (48B)
  __shared__ int eS[256];
  __shared__ int wsum[4];

  const int tid  = threadIdx.x;
  const int lane = tid & 63, wid = tid >> 6;
  W1s[tid] = W1g[tid];

  const int e = blockIdx.x * 256 + tid;
  bool act = false;
  int src = 0, dst = 0;
  float rx = 0.f, ry = 0.f, rz = 0.f, d2 = 0.f;
  if (e < E) {
    src = eidx[e]; dst = eidx[E + e];
    rx = coords[3*src]   - coords[3*dst];
    ry = coords[3*src+1] - coords[3*dst+1];
    rz = coords[3*src+2] - coords[3*dst+2];
    d2 = rx*rx + ry*ry + rz*rz;
    act = (d2 > 0.0f) && (d2 < 36.0f);
  }
  unsigned long long bm = __ballot(act);
  int pfx = __popcll(bm & ((1ull << lane) - 1ull));
  if (lane == 0) wsum[wid] = __popcll(bm);
  __syncthreads();                                   // covers W1s + wsum
  int base = 0;
  #pragma unroll
  for (int w = 0; w < 4; ++w) base += (w < wid) ? wsum[w] : 0;
  const int total = wsum[0] + wsum[1] + wsum[2] + wsum[3];
  const int cpos = base + pfx;

  if (act) {
    float dd  = sqrtf(d2);
    float inv = 1.0f / dd;
    float x = rx*inv, y = ry*inv, z = rz*inv;
    const float A1 = 0.48860251190291992f;  // sqrt(3)/sqrt(4pi)
    const float A2 = 1.09254843059207907f;  // sqrt(15)/sqrt(4pi)
    const float A3 = 0.63078313050504001f;  // sqrt(5)/sqrt(4pi)
    unsigned short* dr = data + (size_t)e * DSTRIDE;
    short8 ys;
    ys[0] = (short)f2bf(A1*x);   ys[1] = (short)f2bf(A1*y);  ys[2] = (short)f2bf(A1*z);
    ys[3] = (short)f2bf(A2*x*z); ys[4] = (short)f2bf(A2*x*y);
    ys[5] = (short)f2bf(A3*(y*y - 0.5f*(x*x + z*z)));
    ys[6] = (short)f2bf(A2*y*z); ys[7] = (short)f2bf(0.5f*A2*(z*z - x*x));
    *(short8*)&dr[64] = ys;
    int slot = atomicAdd(&cnt[dst], 1);
    if (slot < CAP) bucket[dst * CAP + slot] = e;

    // bessel -> hidden: h[j] = gain*silu( (eb@W1)[j]/4 ), float4 LDS reads
    float theta = 0.52359877559829887f * dd;   // pi/6 * d
    float s1 = __sinf(theta), c1 = __cosf(theta);
    float snm = 0.0f, sn = s1;
    float4 hbv[4];
    #pragma unroll
    for (int q = 0; q < 4; ++q) hbv[q] = make_float4(0.f, 0.f, 0.f, 0.f);
    #pragma unroll
    for (int k = 0; k < 16; ++k) {
      #pragma unroll
      for (int q = 0; q < 4; ++q) {
        const float4 w = *((const float4*)&W1s[k*16 + q*4]);
        hbv[q].x = fmaf(sn, w.x, hbv[q].x);
        hbv[q].y = fmaf(sn, w.y, hbv[q].y);
        hbv[q].z = fmaf(sn, w.z, hbv[q].z);
        hbv[q].w = fmaf(sn, w.w, hbv[q].w);
      }
      float sp = 2.0f*c1*sn - snm;
      snm = sn; sn = sp;
    }
    const float scale1 = 2.30940107675850305f * inv * 0.25f;
    float* hrow = &hsS[cpos * 20];
    #pragma unroll
    for (int q = 0; q < 4; ++q) {
      float b[4] = {hbv[q].x, hbv[q].y, hbv[q].z, hbv[q].w};
      #pragma unroll
      for (int r = 0; r < 4; ++r) {
        float p = b[r] * scale1;
        hrow[q*4 + r] = 1.679177f * p / (1.0f + __expf(-p));
      }
    }
    unsigned short* xrow = &xsS[cpos * 24];
    #pragma unroll
    for (int cc = 0; cc < 4; ++cc) {
      float4 xv = *(const float4*)&xfeat[src*16 + cc*4];
      xrow[cc*4+0] = f2bf(xv.x); xrow[cc*4+1] = f2bf(xv.y);
      xrow[cc*4+2] = f2bf(xv.z); xrow[cc*4+3] = f2bf(xv.w);
    }
    eS[cpos] = e;
  }
  const int padded = (total + 15) & ~15;
  if (tid >= total && tid < padded) {       // zero pad rows
    #pragma unroll
    for (int j = 0; j < 16; ++j) hsS[tid*20 + j] = 0.0f;
    #pragma unroll
    for (int j = 0; j < 16; ++j) xsS[tid*24 + j] = 0;
  }
  __syncthreads();

  // ---- MFMA GEMM [padded,256] x [256,48] ----
  short8 bfr[8][3];
  #pragma unroll
  for (int s = 0; s < 8; ++s)
    #pragma unroll
    for (int t = 0; t < 3; ++t)
      bfr[s][t] = *(const short8*)&w2f[(size_t)((s*3 + t)*64 + lane) * 8];

  const int ngroups = padded >> 4;
  const int ma = lane & 15, kq = lane >> 4;
  const int c0 = (kq & 1) * 8;
  for (int g = wid; g < ngroups; g += 4) {
    const int cidx = g*16 + ma;
    const float* hrow = &hsS[cidx * 20];
    const unsigned short* xrow = &xsS[cidx * 24];
    float xsf[8];
    #pragma unroll
    for (int j = 0; j < 8; ++j) xsf[j] = bf2f(xrow[c0 + j]);

    f32x4 acc0 = {0,0,0,0}, acc1 = {0,0,0,0}, acc2 = {0,0,0,0};
    #pragma unroll
    for (int s = 0; s < 8; ++s) {
      const float hk = hrow[2*s + (kq >> 1)];
      short8 a;
      #pragma unroll
      for (int j = 0; j < 8; ++j) a[j] = (short)f2bf(hk * xsf[j]);
      acc0 = __builtin_amdgcn_mfma_f32_16x16x32_bf16(a, bfr[s][0], acc0, 0, 0, 0);
      acc1 = __builtin_amdgcn_mfma_f32_16x16x32_bf16(a, bfr[s][1], acc1, 0, 0, 0);
      acc2 = __builtin_amdgcn_mfma_f32_16x16x32_bf16(a, bfr[s][2], acc2, 0, 0, 0);
    }
    // D layout: row = kq*4 + r, col = lane&15  (m89-verified)
    const float sc = 0.00390625f;  // 1/256
    #pragma unroll
    for (int r = 0; r < 4; ++r) {
      const int cr = g*16 + kq*4 + r;
      if (cr < total) {
        unsigned short* dr = data + (size_t)eS[cr] * DSTRIDE;
        u16x4 vv;
        vv[0] = f2bf(acc0[r] * sc);
        vv[1] = f2bf(acc1[r] * sc);
        vv[2] = f2bf(acc2[r] * sc);
        vv[3] = 0;
        *(u16x4*)&dr[ma * 4] = vv;
      }
    }
  }
}

// ---- K2: gather (16 threads per node iterate its bucket; no pointer chase) ----
__global__ __launch_bounds__(256)
void gather_kernel(const unsigned short* __restrict__ data,
                   const int* __restrict__ cnt,
                   const int* __restrict__ bucket,
                   float* __restrict__ out, int N)
{
  int gid = blockIdx.x * 256 + threadIdx.x;
  int node = gid >> 4, h = gid & 15;
  if (node >= N) return;

  float a0 = 0.f;
  float a10 = 0.f, a11 = 0.f, a12 = 0.f;
  float a20 = 0.f, a21 = 0.f, a22 = 0.f, a23 = 0.f, a24 = 0.f;

  int c = cnt[node];
  c = c < CAP ? c : CAP;
  const int* bk = &bucket[node * CAP];
  for (int i = 0; i < c; ++i) {
    const int p = bk[i];                      // broadcast across the 16 threads
    const unsigned short* dr = data + (size_t)p * DSTRIDE;
    u16x4 vv = *(const u16x4*)&dr[h * 4];
    short8 yv = *(const short8*)&dr[64];
    float v0 = bf2f(vv[0]), v1 = bf2f(vv[1]), v2 = bf2f(vv[2]);
    a0  += v0;
    a10 = fmaf(v1, bf2f((unsigned short)yv[0]), a10);
    a11 = fmaf(v1, bf2f((unsigned short)yv[1]), a11);
    a12 = fmaf(v1, bf2f((unsigned short)yv[2]), a12);
    a20 = fmaf(v2, bf2f((unsigned short)yv[3]), a20);
    a21 = fmaf(v2, bf2f((unsigned short)yv[4]), a21);
    a22 = fmaf(v2, bf2f((unsigned short)yv[5]), a22);
    a23 = fmaf(v2, bf2f((unsigned short)yv[6]), a23);
    a24 = fmaf(v2, bf2f((unsigned short)yv[7]), a24);
  }

  float* o = out + (size_t)node * 144;
  o[h] = a0 * 0.28209479177387814f;   // Y0 constant folded here
  o[16 + h*3 + 0] = a10;
  o[16 + h*3 + 1] = a11;
  o[16 + h*3 + 2] = a12;
  o[64 + h*5 + 0] = a20;
  o[64 + h*5 + 1] = a21;
  o[64 + h*5 + 2] = a22;
  o[64 + h*5 + 3] = a23;
  o[64 + h*5 + 4] = a24;
}

extern "C" void kernel_launch(void* const* d_in, const int* in_sizes, int n_in,
                              void* d_out, int out_size, void* d_ws, size_t ws_size,
                              hipStream_t stream) {
  const float* xfeat  = (const float*)d_in[0];
  const float* coords = (const float*)d_in[1];
  const int*   eidx   = (const int*)d_in[2];
  const float* W1     = (const float*)d_in[3];
  const float* W2     = (const float*)d_in[4];
  float* out = (float*)d_out;

  const int E = in_sizes[2] / 2;
  const int N = out_size / 144;

  // ws layout (16B-aligned): data bf16[E][72] | cnt[N pad4] | bucket[N][CAP] | w2f
  char* ws = (char*)d_ws;
  size_t off_cnt    = (size_t)E * DSTRIDE * sizeof(unsigned short);
  size_t off_bucket = off_cnt + (size_t)((N + 3) & ~3) * sizeof(int);
  size_t off_w2f    = off_bucket + (size_t)N * CAP * sizeof(int);
  unsigned short* data = (unsigned short*)ws;
  int* cnt    = (int*)(ws + off_cnt);
  int* bucket = (int*)(ws + off_bucket);
  unsigned short* w2f = (unsigned short*)(ws + off_w2f);

  int pblk = (N + 255) / 256;
  if (pblk < 6) pblk = 6;
  prep_kernel<<<pblk, 256, 0, stream>>>(W2, w2f, cnt, N);
  interact_kernel<<<(E + 255) / 256, 256, 0, stream>>>(xfeat, coords, eidx, W1,
                                                       w2f, data, cnt, bucket, E);
  gather_kernel<<<(N * 16 + 255) / 256, 256, 0, stream>>>(data, cnt, bucket, out, N);
}

// Round 7
// 39.485 us; speedup vs baseline: 4.6176x; 1.0955x over previous
//
#include <hip/hip_runtime.h>
#include <hip/hip_bf16.h>
#include <math.h>

// InteractionBlock R7 == R6 with ONE change: interact __launch_bounds__(256,3).
// R6 post-mortem: (256,4) caps VGPR at 128 < the ~135 live regs the MFMA phase
// needs (bfr[8][3] short8 = 96 alone); compiler shrank to 64 regs (seen on R5's
// fused twin) by re-materializing B-frags from global inside the K-loop
// (~480MB L2 traffic). (256,3) -> ~170 cap -> frags stay resident.
//  prep:  cnt[]=0 + pack W2 into pre-swizzled bf16 MFMA B-fragments.
//  K1:    geometry/bessel-MLP -> ballot compaction -> MFMA GEMM
//         [E,256](q = h (x) xs) x [256,48](W2 frags in VGPRs) -> factored bf16
//         message rows data[e] = { v[16][4], Y1..Y8 }; bucket-CSR scatter index.
//  K2:    per-node gather over bucket entries (independent loads, no chase).

typedef __attribute__((ext_vector_type(8))) short short8;
typedef __attribute__((ext_vector_type(4))) float f32x4;
typedef __attribute__((ext_vector_type(4))) unsigned short u16x4;

#define DSTRIDE 72   // ushorts per data row (144 B, 16B-aligned)
#define CAP 64       // bucket capacity per node (active degree ~Poisson(6.86))

static __device__ __forceinline__ unsigned short f2bf(float f) {
  __hip_bfloat16 h = __float2bfloat16(f);   // RNE; pairs fuse to v_cvt_pk_bf16_f32
  return __builtin_bit_cast(unsigned short, h);
}
static __device__ __forceinline__ float bf2f(unsigned short s) {
  unsigned u = ((unsigned)s) << 16;
  return __builtin_bit_cast(float, u);
}

// ---- prep: cnt=0 + W2 -> bf16 B-fragments ----
// frag fi = s*3+t (s=k-step 0..7, t=n-tile 0..2); entry (fi,lane,j):
//   k_global = s*32 + (lane>>4)*8 + j, n = t*16 + (lane&15)
//   W2r[k][n] = W2[kk*768 + t*256 + c*16 + h], kk=k>>4, c=k&15, h=lane&15
__global__ __launch_bounds__(256)
void prep_kernel(const float* __restrict__ W2, unsigned short* __restrict__ w2f,
                 int* __restrict__ cnt, int N) {
  int gid = blockIdx.x * 256 + threadIdx.x;
  if (gid < N) cnt[gid] = 0;
  if (gid < 24 * 64) {
    int fi = gid >> 6, lane = gid & 63;
    int s = fi / 3, t = fi - 3 * s;
    int h = lane & 15, kq = lane >> 4;
    short8 pack;
    #pragma unroll
    for (int j = 0; j < 8; ++j) {
      int kg = s * 32 + kq * 8 + j;
      int kk = kg >> 4, c = kg & 15;
      pack[j] = (short)f2bf(W2[kk * 768 + t * 256 + c * 16 + h]);
    }
    *(short8*)&w2f[(size_t)gid * 8] = pack;
  }
}

// ---- K1: per-edge features + compaction + MFMA GEMM + factored-message write ----
__global__ __launch_bounds__(256, 3)
void interact_kernel(const float* __restrict__ xfeat,
                     const float* __restrict__ coords,
                     const int* __restrict__ eidx,
                     const float* __restrict__ W1g,
                     const unsigned short* __restrict__ w2f,
                     unsigned short* __restrict__ data,  // [E][72] bf16
                     int* __restrict__ cnt,              // [N] zeroed
                     int* __restrict__ bucket,           // [N][CAP]
                     int E)
{
  __shared__ __align__(16) float W1s[256];
  __shared__ float hsS[256 * 20];                        // stride 20 f32 (80B)
  __shared__ __align__(16) unsigned short xsS[256 * 24]; // stride 24 ush (48B)
  __shared__ int eS[256];
  __shared__ int wsum[4];

  const int tid  = threadIdx.x;
  const int lane = tid & 63, wid = tid >> 6;
  W1s[tid] = W1g[tid];

  const int e = blockIdx.x * 256 + tid;
  bool act = false;
  int src = 0, dst = 0;
  float rx = 0.f, ry = 0.f, rz = 0.f, d2 = 0.f;
  if (e < E) {
    src = eidx[e]; dst = eidx[E + e];
    rx = coords[3*src]   - coords[3*dst];
    ry = coords[3*src+1] - coords[3*dst+1];
    rz = coords[3*src+2] - coords[3*dst+2];
    d2 = rx*rx + ry*ry + rz*rz;
    act = (d2 > 0.0f) && (d2 < 36.0f);
  }
  unsigned long long bm = __ballot(act);
  int pfx = __popcll(bm & ((1ull << lane) - 1ull));
  if (lane == 0) wsum[wid] = __popcll(bm);
  __syncthreads();                                   // covers W1s + wsum
  int base = 0;
  #pragma unroll
  for (int w = 0; w < 4; ++w) base += (w < wid) ? wsum[w] : 0;
  const int total = wsum[0] + wsum[1] + wsum[2] + wsum[3];
  const int cpos = base + pfx;

  if (act) {
    float dd  = sqrtf(d2);
    float inv = 1.0f / dd;
    float x = rx*inv, y = ry*inv, z = rz*inv;
    const float A1 = 0.48860251190291992f;  // sqrt(3)/sqrt(4pi)
    const float A2 = 1.09254843059207907f;  // sqrt(15)/sqrt(4pi)
    const float A3 = 0.63078313050504001f;  // sqrt(5)/sqrt(4pi)
    unsigned short* dr = data + (size_t)e * DSTRIDE;
    short8 ys;
    ys[0] = (short)f2bf(A1*x);   ys[1] = (short)f2bf(A1*y);  ys[2] = (short)f2bf(A1*z);
    ys[3] = (short)f2bf(A2*x*z); ys[4] = (short)f2bf(A2*x*y);
    ys[5] = (short)f2bf(A3*(y*y - 0.5f*(x*x + z*z)));
    ys[6] = (short)f2bf(A2*y*z); ys[7] = (short)f2bf(0.5f*A2*(z*z - x*x));
    *(short8*)&dr[64] = ys;
    int slot = atomicAdd(&cnt[dst], 1);
    if (slot < CAP) bucket[dst * CAP + slot] = e;

    // bessel -> hidden: h[j] = gain*silu( (eb@W1)[j]/4 ), float4 LDS reads
    float theta = 0.52359877559829887f * dd;   // pi/6 * d
    float s1 = __sinf(theta), c1 = __cosf(theta);
    float snm = 0.0f, sn = s1;
    float4 hbv[4];
    #pragma unroll
    for (int q = 0; q < 4; ++q) hbv[q] = make_float4(0.f, 0.f, 0.f, 0.f);
    #pragma unroll
    for (int k = 0; k < 16; ++k) {
      #pragma unroll
      for (int q = 0; q < 4; ++q) {
        const float4 w = *((const float4*)&W1s[k*16 + q*4]);
        hbv[q].x = fmaf(sn, w.x, hbv[q].x);
        hbv[q].y = fmaf(sn, w.y, hbv[q].y);
        hbv[q].z = fmaf(sn, w.z, hbv[q].z);
        hbv[q].w = fmaf(sn, w.w, hbv[q].w);
      }
      float sp = 2.0f*c1*sn - snm;
      snm = sn; sn = sp;
    }
    const float scale1 = 2.30940107675850305f * inv * 0.25f;
    float* hrow = &hsS[cpos * 20];
    #pragma unroll
    for (int q = 0; q < 4; ++q) {
      float b[4] = {hbv[q].x, hbv[q].y, hbv[q].z, hbv[q].w};
      #pragma unroll
      for (int r = 0; r < 4; ++r) {
        float p = b[r] * scale1;
        hrow[q*4 + r] = 1.679177f * p / (1.0f + __expf(-p));
      }
    }
    unsigned short* xrow = &xsS[cpos * 24];
    #pragma unroll
    for (int cc = 0; cc < 4; ++cc) {
      float4 xv = *(const float4*)&xfeat[src*16 + cc*4];
      xrow[cc*4+0] = f2bf(xv.x); xrow[cc*4+1] = f2bf(xv.y);
      xrow[cc*4+2] = f2bf(xv.z); xrow[cc*4+3] = f2bf(xv.w);
    }
    eS[cpos] = e;
  }
  const int padded = (total + 15) & ~15;
  if (tid >= total && tid < padded) {       // zero pad rows
    #pragma unroll
    for (int j = 0; j < 16; ++j) hsS[tid*20 + j] = 0.0f;
    #pragma unroll
    for (int j = 0; j < 16; ++j) xsS[tid*24 + j] = 0;
  }
  __syncthreads();

  // ---- MFMA GEMM [padded,256] x [256,48] ----
  short8 bfr[8][3];
  #pragma unroll
  for (int s = 0; s < 8; ++s)
    #pragma unroll
    for (int t = 0; t < 3; ++t)
      bfr[s][t] = *(const short8*)&w2f[(size_t)((s*3 + t)*64 + lane) * 8];

  const int ngroups = padded >> 4;
  const int ma = lane & 15, kq = lane >> 4;
  const int c0 = (kq & 1) * 8;
  for (int g = wid; g < ngroups; g += 4) {
    const int cidx = g*16 + ma;
    const float* hrow = &hsS[cidx * 20];
    const unsigned short* xrow = &xsS[cidx * 24];
    float xsf[8];
    #pragma unroll
    for (int j = 0; j < 8; ++j) xsf[j] = bf2f(xrow[c0 + j]);

    f32x4 acc0 = {0,0,0,0}, acc1 = {0,0,0,0}, acc2 = {0,0,0,0};
    #pragma unroll
    for (int s = 0; s < 8; ++s) {
      const float hk = hrow[2*s + (kq >> 1)];
      short8 a;
      #pragma unroll
      for (int j = 0; j < 8; ++j) a[j] = (short)f2bf(hk * xsf[j]);
      acc0 = __builtin_amdgcn_mfma_f32_16x16x32_bf16(a, bfr[s][0], acc0, 0, 0, 0);
      acc1 = __builtin_amdgcn_mfma_f32_16x16x32_bf16(a, bfr[s][1], acc1, 0, 0, 0);
      acc2 = __builtin_amdgcn_mfma_f32_16x16x32_bf16(a, bfr[s][2], acc2, 0, 0, 0);
    }
    // D layout: row = kq*4 + r, col = lane&15  (m89-verified)
    const float sc = 0.00390625f;  // 1/256
    #pragma unroll
    for (int r = 0; r < 4; ++r) {
      const int cr = g*16 + kq*4 + r;
      if (cr < total) {
        unsigned short* dr = data + (size_t)eS[cr] * DSTRIDE;
        u16x4 vv;
        vv[0] = f2bf(acc0[r] * sc);
        vv[1] = f2bf(acc1[r] * sc);
        vv[2] = f2bf(acc2[r] * sc);
        vv[3] = 0;
        *(u16x4*)&dr[ma * 4] = vv;
      }
    }
  }
}

// ---- K2: gather (16 threads per node iterate its bucket; no pointer chase) ----
__global__ __launch_bounds__(256)
void gather_kernel(const unsigned short* __restrict__ data,
                   const int* __restrict__ cnt,
                   const int* __restrict__ bucket,
                   float* __restrict__ out, int N)
{
  int gid = blockIdx.x * 256 + threadIdx.x;
  int node = gid >> 4, h = gid & 15;
  if (node >= N) return;

  float a0 = 0.f;
  float a10 = 0.f, a11 = 0.f, a12 = 0.f;
  float a20 = 0.f, a21 = 0.f, a22 = 0.f, a23 = 0.f, a24 = 0.f;

  int c = cnt[node];
  c = c < CAP ? c : CAP;
  const int* bk = &bucket[node * CAP];
  for (int i = 0; i < c; ++i) {
    const int p = bk[i];                      // broadcast across the 16 threads
    const unsigned short* dr = data + (size_t)p * DSTRIDE;
    u16x4 vv = *(const u16x4*)&dr[h * 4];
    short8 yv = *(const short8*)&dr[64];
    float v0 = bf2f(vv[0]), v1 = bf2f(vv[1]), v2 = bf2f(vv[2]);
    a0  += v0;
    a10 = fmaf(v1, bf2f((unsigned short)yv[0]), a10);
    a11 = fmaf(v1, bf2f((unsigned short)yv[1]), a11);
    a12 = fmaf(v1, bf2f((unsigned short)yv[2]), a12);
    a20 = fmaf(v2, bf2f((unsigned short)yv[3]), a20);
    a21 = fmaf(v2, bf2f((unsigned short)yv[4]), a21);
    a22 = fmaf(v2, bf2f((unsigned short)yv[5]), a22);
    a23 = fmaf(v2, bf2f((unsigned short)yv[6]), a23);
    a24 = fmaf(v2, bf2f((unsigned short)yv[7]), a24);
  }

  float* o = out + (size_t)node * 144;
  o[h] = a0 * 0.28209479177387814f;   // Y0 constant folded here
  o[16 + h*3 + 0] = a10;
  o[16 + h*3 + 1] = a11;
  o[16 + h*3 + 2] = a12;
  o[64 + h*5 + 0] = a20;
  o[64 + h*5 + 1] = a21;
  o[64 + h*5 + 2] = a22;
  o[64 + h*5 + 3] = a23;
  o[64 + h*5 + 4] = a24;
}

extern "C" void kernel_launch(void* const* d_in, const int* in_sizes, int n_in,
                              void* d_out, int out_size, void* d_ws, size_t ws_size,
                              hipStream_t stream) {
  const float* xfeat  = (const float*)d_in[0];
  const float* coords = (const float*)d_in[1];
  const int*   eidx   = (const int*)d_in[2];
  const float* W1     = (const float*)d_in[3];
  const float* W2     = (const float*)d_in[4];
  float* out = (float*)d_out;

  const int E = in_sizes[2] / 2;
  const int N = out_size / 144;

  // ws layout (16B-aligned): data bf16[E][72] | cnt[N pad4] | bucket[N][CAP] | w2f
  char* ws = (char*)d_ws;
  size_t off_cnt    = (size_t)E * DSTRIDE * sizeof(unsigned short);
  size_t off_bucket = off_cnt + (size_t)((N + 3) & ~3) * sizeof(int);
  size_t off_w2f    = off_bucket + (size_t)N * CAP * sizeof(int);
  unsigned short* data = (unsigned short*)ws;
  int* cnt    = (int*)(ws + off_cnt);
  int* bucket = (int*)(ws + off_bucket);
  unsigned short* w2f = (unsigned short*)(ws + off_w2f);

  int pblk = (N + 255) / 256;
  if (pblk < 6) pblk = 6;
  prep_kernel<<<pblk, 256, 0, stream>>>(W2, w2f, cnt, N);
  interact_kernel<<<(E + 255) / 256, 256, 0, stream>>>(xfeat, coords, eidx, W1,
                                                       w2f, data, cnt, bucket, E);
  gather_kernel<<<(N * 16 + 255) / 256, 256, 0, stream>>>(data, cnt, bucket, out, N);
}